// Round 1
// baseline (5636.045 us; speedup 1.0000x reference)
//
#include <hip/hip_runtime.h>
#include <cstddef>

// Problem constants
#define NN_ 4096      // nodes
#define TT_ 64        // tokens per node
#define DIN 300       // embedding dim
#define RH_ 256       // rnn hidden
#define G3_ 768       // 3*RH
#define BB_ 64        // graphs
#define EE_ 65536     // edges

// ---------------- zero fill ----------------
__global__ void k_zero(float* __restrict__ p, long n) {
    for (long i = (long)blockIdx.x * blockDim.x + threadIdx.x; i < n;
         i += (long)gridDim.x * blockDim.x)
        p[i] = 0.f;
}

// ---------------- xp = gather(emb)[:,t] @ W.T + b  -> XP[4096][768] ----------------
// W is [768][300] row-major (dot along contiguous k). Tiles 64x64, BK=32.
__global__ __launch_bounds__(256) void k_xp(
    const int* __restrict__ tokens, const float* __restrict__ emb,
    const float* __restrict__ W, const float* __restrict__ bias,
    float* __restrict__ XP, int t)
{
    __shared__ float As[32][68];
    __shared__ float Bs[32][68];
    __shared__ int toks[64];
    int tid = threadIdx.x;
    int n0 = blockIdx.x * 64, c0 = blockIdx.y * 64;
    if (tid < 64) toks[tid] = tokens[(n0 + tid) * TT_ + t];
    __syncthreads();

    float acc[4][4] = {};
    int tx = tid & 15, ty = tid >> 4;
    int q = tid & 7, m = tid >> 3;

    for (int kk = 0; kk < DIN; kk += 32) {
        int k4 = kk + q * 4;
        float4 av0 = {0,0,0,0}, av1 = {0,0,0,0}, bv0 = {0,0,0,0}, bv1 = {0,0,0,0};
        if (k4 < DIN) {
            av0 = *(const float4*)(emb + (size_t)toks[m] * DIN + k4);
            av1 = *(const float4*)(emb + (size_t)toks[m + 32] * DIN + k4);
            bv0 = *(const float4*)(W + (size_t)(c0 + m) * DIN + k4);
            bv1 = *(const float4*)(W + (size_t)(c0 + m + 32) * DIN + k4);
        }
        __syncthreads();
        int kb = q * 4;
        #pragma unroll
        for (int i = 0; i < 4; i++) {
            As[kb + i][m]      = ((const float*)&av0)[i];
            As[kb + i][m + 32] = ((const float*)&av1)[i];
            Bs[kb + i][m]      = ((const float*)&bv0)[i];
            Bs[kb + i][m + 32] = ((const float*)&bv1)[i];
        }
        __syncthreads();
        #pragma unroll 8
        for (int k = 0; k < 32; k++) {
            float4 a4 = *(const float4*)&As[k][ty * 4];
            float4 b4 = *(const float4*)&Bs[k][tx * 4];
            const float* ar = (const float*)&a4;
            const float* br = (const float*)&b4;
            #pragma unroll
            for (int i = 0; i < 4; i++)
                #pragma unroll
                for (int j = 0; j < 4; j++)
                    acc[i][j] = fmaf(ar[i], br[j], acc[i][j]);
        }
    }
    #pragma unroll
    for (int i = 0; i < 4; i++) {
        int n = n0 + ty * 4 + i;
        #pragma unroll
        for (int j = 0; j < 4; j++) {
            int c = c0 + tx * 4 + j;
            XP[(size_t)n * G3_ + c] = acc[i][j] + bias[c];
        }
    }
}

// ---------------- fused recurrent GEMM + GRU gates ----------------
// gh = h @ W_hh.T + b_hh (3 gate chunks), then h' = (1-z)*n + z*h.
// hin/hout: [4096][512] (cols 0..255 used), ping-pong. Grid (64,4).
__global__ __launch_bounds__(256) void k_gru(
    const float* __restrict__ hin, const float* __restrict__ XP,
    const float* __restrict__ W, const float* __restrict__ bias,
    float* __restrict__ hout)
{
    __shared__ float As[32][68];
    __shared__ float Bs[3][32][68];
    int tid = threadIdx.x;
    int n0 = blockIdx.x * 64, c0 = blockIdx.y * 64;
    float acc[3][4][4] = {};
    int tx = tid & 15, ty = tid >> 4;
    int q = tid & 7, m = tid >> 3;

    for (int kk = 0; kk < RH_; kk += 32) {
        int k4 = kk + q * 4;
        float4 av0 = *(const float4*)(hin + (size_t)(n0 + m) * 512 + k4);
        float4 av1 = *(const float4*)(hin + (size_t)(n0 + m + 32) * 512 + k4);
        float4 bv[3][2];
        #pragma unroll
        for (int g = 0; g < 3; g++) {
            bv[g][0] = *(const float4*)(W + (size_t)(g * 256 + c0 + m) * RH_ + k4);
            bv[g][1] = *(const float4*)(W + (size_t)(g * 256 + c0 + m + 32) * RH_ + k4);
        }
        __syncthreads();
        int kb = q * 4;
        #pragma unroll
        for (int i = 0; i < 4; i++) {
            As[kb + i][m]      = ((const float*)&av0)[i];
            As[kb + i][m + 32] = ((const float*)&av1)[i];
        }
        #pragma unroll
        for (int g = 0; g < 3; g++)
            #pragma unroll
            for (int i = 0; i < 4; i++) {
                Bs[g][kb + i][m]      = ((const float*)&bv[g][0])[i];
                Bs[g][kb + i][m + 32] = ((const float*)&bv[g][1])[i];
            }
        __syncthreads();
        #pragma unroll 4
        for (int k = 0; k < 32; k++) {
            float4 a4 = *(const float4*)&As[k][ty * 4];
            const float* ar = (const float*)&a4;
            #pragma unroll
            for (int g = 0; g < 3; g++) {
                float4 b4 = *(const float4*)&Bs[g][k][tx * 4];
                const float* br = (const float*)&b4;
                #pragma unroll
                for (int i = 0; i < 4; i++)
                    #pragma unroll
                    for (int j = 0; j < 4; j++)
                        acc[g][i][j] = fmaf(ar[i], br[j], acc[g][i][j]);
            }
        }
    }
    #pragma unroll
    for (int i = 0; i < 4; i++) {
        int n = n0 + ty * 4 + i;
        size_t xb = (size_t)n * G3_;
        #pragma unroll
        for (int j = 0; j < 4; j++) {
            int c = c0 + tx * 4 + j;
            float hr = acc[0][i][j] + bias[c];
            float hz = acc[1][i][j] + bias[256 + c];
            float hn = acc[2][i][j] + bias[512 + c];
            float r  = 1.f / (1.f + __expf(-(XP[xb + c] + hr)));
            float z  = 1.f / (1.f + __expf(-(XP[xb + 256 + c] + hz)));
            float nv = tanhf(XP[xb + 512 + c] + r * hn);
            hout[(size_t)n * 512 + c] = (1.f - z) * nv + z * hin[(size_t)n * 512 + c];
        }
    }
}

// ---------------- backward GRU single cell from h0=0 -> HA[:,256:512] ----------------
__global__ void k_bwd(const float* __restrict__ XP, const float* __restrict__ bhh,
                      float* __restrict__ HA)
{
    for (int idx = blockIdx.x * blockDim.x + threadIdx.x; idx < NN_ * 256;
         idx += gridDim.x * blockDim.x) {
        int n = idx >> 8, j = idx & 255;
        size_t xb = (size_t)n * G3_;
        float r  = 1.f / (1.f + __expf(-(XP[xb + j] + bhh[j])));
        float z  = 1.f / (1.f + __expf(-(XP[xb + 256 + j] + bhh[256 + j])));
        float nv = tanhf(XP[xb + 512 + j] + r * bhh[512 + j]);
        HA[(size_t)n * 512 + 256 + j] = (1.f - z) * nv;
    }
}

// ---------------- edge scatter: agg[dst] += h[src] ----------------
__global__ void k_scatter(const float* __restrict__ h, const int* __restrict__ src,
                          const int* __restrict__ dst, float* __restrict__ agg,
                          int logK, int strideH)
{
    int K = 1 << logK;
    long total = (long)EE_ << logK;
    for (long idx = (long)blockIdx.x * blockDim.x + threadIdx.x; idx < total;
         idx += (long)gridDim.x * blockDim.x) {
        int e = (int)(idx >> logK);
        int c = (int)(idx & (K - 1));
        atomicAdd(&agg[(long)dst[e] * K + c], h[(long)src[e] * strideH + c]);
    }
}

// ---------------- GCN GEMM: out = relu(A @ W + b), W is [K][256] row-major ----------------
__global__ __launch_bounds__(256) void k_gcn(
    const float* __restrict__ A, const float* __restrict__ W,
    const float* __restrict__ bias, float* __restrict__ out, int K)
{
    __shared__ float As[32][68];
    __shared__ float Bs[32][68];
    int tid = threadIdx.x;
    int n0 = blockIdx.x * 64, c0 = blockIdx.y * 64;
    float acc[4][4] = {};
    int tx = tid & 15, ty = tid >> 4;
    int q = tid & 7, m = tid >> 3;
    int jj = tid & 15, kr = tid >> 4;

    for (int kk = 0; kk < K; kk += 32) {
        int k4 = kk + q * 4;
        float4 av0 = *(const float4*)(A + (size_t)(n0 + m) * K + k4);
        float4 av1 = *(const float4*)(A + (size_t)(n0 + m + 32) * K + k4);
        float4 bv0 = *(const float4*)(W + (size_t)(kk + kr) * 256 + c0 + jj * 4);
        float4 bv1 = *(const float4*)(W + (size_t)(kk + kr + 16) * 256 + c0 + jj * 4);
        __syncthreads();
        int kb = q * 4;
        #pragma unroll
        for (int i = 0; i < 4; i++) {
            As[kb + i][m]      = ((const float*)&av0)[i];
            As[kb + i][m + 32] = ((const float*)&av1)[i];
        }
        *(float4*)&Bs[kr][jj * 4]      = bv0;
        *(float4*)&Bs[kr + 16][jj * 4] = bv1;
        __syncthreads();
        #pragma unroll 8
        for (int k = 0; k < 32; k++) {
            float4 a4 = *(const float4*)&As[k][ty * 4];
            float4 b4 = *(const float4*)&Bs[k][tx * 4];
            const float* ar = (const float*)&a4;
            const float* br = (const float*)&b4;
            #pragma unroll
            for (int i = 0; i < 4; i++)
                #pragma unroll
                for (int j = 0; j < 4; j++)
                    acc[i][j] = fmaf(ar[i], br[j], acc[i][j]);
        }
    }
    #pragma unroll
    for (int i = 0; i < 4; i++) {
        int n = n0 + ty * 4 + i;
        #pragma unroll
        for (int j = 0; j < 4; j++) {
            int c = c0 + tx * 4 + j;
            out[(size_t)n * 256 + c] = fmaxf(acc[i][j] + bias[c], 0.f);
        }
    }
}

// ---------------- readout ----------------
__global__ void k_readout(const float* __restrict__ h, const int* __restrict__ gid,
                          const int* __restrict__ ntype, float* __restrict__ out,
                          float* __restrict__ cnt)
{
    for (int idx = blockIdx.x * blockDim.x + threadIdx.x; idx < NN_ * 256;
         idx += gridDim.x * blockDim.x) {
        int n = idx >> 8, c = idx & 255;
        float v = h[idx];
        int g = gid[n], t = ntype[n];
        if (t == 0) {
            atomicAdd(&out[g * 256 + c], v);
            if (c == 0) atomicAdd(&cnt[g], 1.f);
        } else if (t == 1) {
            atomicAdd(&out[16384 + g * 256 + c], v);
        } else {
            atomicAdd(&out[32768 + g * 256 + c], v);
        }
    }
}

__global__ void k_finalize(float* __restrict__ out, const float* __restrict__ cnt)
{
    int idx = blockIdx.x * blockDim.x + threadIdx.x;  // < 16384
    out[idx] /= cnt[idx >> 8];
}

// ---------------- host ----------------
extern "C" void kernel_launch(void* const* d_in, const int* in_sizes, int n_in,
                              void* d_out, int out_size, void* d_ws, size_t ws_size,
                              hipStream_t stream)
{
    const int*   tokens = (const int*)d_in[0];
    const int*   esrc   = (const int*)d_in[1];
    const int*   edst   = (const int*)d_in[2];
    const int*   gid    = (const int*)d_in[3];
    const int*   ntype  = (const int*)d_in[4];
    const float* emb    = (const float*)d_in[5];
    const float* W_ih_f = (const float*)d_in[6];
    const float* W_hh_f = (const float*)d_in[7];
    const float* b_ih_f = (const float*)d_in[8];
    const float* b_hh_f = (const float*)d_in[9];
    const float* W_ih_b = (const float*)d_in[10];
    const float* W_hh_b = (const float*)d_in[11];
    const float* b_ih_b = (const float*)d_in[12];
    const float* b_hh_b = (const float*)d_in[13];
    const float* Wg[4]  = {(const float*)d_in[14], (const float*)d_in[16],
                           (const float*)d_in[18], (const float*)d_in[20]};
    const float* bg[4]  = {(const float*)d_in[15], (const float*)d_in[17],
                           (const float*)d_in[19], (const float*)d_in[21]};
    float* out = (float*)d_out;

    float* HA  = (float*)d_ws;                 // [4096][512]  h_fwd | h_bwd
    float* HB  = HA + (size_t)NN_ * 512;       // [4096][512]  ping-pong / agg
    float* XP  = HB + (size_t)NN_ * 512;       // [4096][768]
    float* CNT = XP + (size_t)NN_ * G3_;       // [64]

    // h0 = 0 (also clears bwd region)
    k_zero<<<2048, 256, 0, stream>>>(HA, (long)NN_ * 512);

    // GRU scan over T (ping-pong HA/HB; after t=63 result lands in HA)
    for (int t = 0; t < TT_; t++) {
        const float* cur = (t & 1) ? HB : HA;
        float*       nxt = (t & 1) ? HA : HB;
        k_xp<<<dim3(64, 12), 256, 0, stream>>>(tokens, emb, W_ih_f, b_ih_f, XP, t);
        k_gru<<<dim3(64, 4), 256, 0, stream>>>(cur, XP, W_hh_f, b_hh_f, nxt);
    }

    // backward GRU: one cell on x[:, T-1] from zero state
    k_xp<<<dim3(64, 12), 256, 0, stream>>>(tokens, emb, W_ih_b, b_ih_b, XP, TT_ - 1);
    k_bwd<<<2048, 256, 0, stream>>>(XP, b_hh_b, HA);

    // 4 GCN layers: agg in HB, output back to HA (stride 256 after layer 1)
    for (int l = 0; l < 4; l++) {
        int K = (l == 0) ? 512 : 256;
        int logK = (l == 0) ? 9 : 8;
        k_zero<<<2048, 256, 0, stream>>>(HB, (long)NN_ * K);
        k_scatter<<<4096, 256, 0, stream>>>(HA, esrc, edst, HB, logK, K);
        k_gcn<<<dim3(64, 4), 256, 0, stream>>>(HB, Wg[l], bg[l], HA, K);
    }

    // readout
    k_zero<<<256, 256, 0, stream>>>(out, 49152);
    k_zero<<<1, 64, 0, stream>>>(CNT, 64);
    k_readout<<<2048, 256, 0, stream>>>(HA, gid, ntype, out, CNT);
    k_finalize<<<64, 256, 0, stream>>>(out, CNT);
}

// Round 2
// 1504.631 us; speedup vs baseline: 3.7458x; 3.7458x over previous
//
#include <hip/hip_runtime.h>
#include <cstddef>

// Problem constants
#define NN_ 4096      // nodes
#define TT_ 64        // tokens per node
#define DIN 300       // embedding dim
#define DINP 320      // padded to mult of 32
#define RH_ 256       // rnn hidden
#define G3_ 768       // 3*RH
#define BB_ 64        // graphs
#define EE_ 65536     // edges

typedef short bf16x8 __attribute__((ext_vector_type(8)));
typedef float f32x4 __attribute__((ext_vector_type(4)));
typedef unsigned short u16;

__device__ __forceinline__ u16 f2bf(float f) {
    unsigned u = __builtin_bit_cast(unsigned, f);
    u += 0x7fff + ((u >> 16) & 1);          // RNE
    return (u16)(u >> 16);
}

__device__ __forceinline__ void gload16(const void* g, void* l) {
    __builtin_amdgcn_global_load_lds(
        (const __attribute__((address_space(1))) unsigned*)g,
        (__attribute__((address_space(3))) unsigned*)l, 16, 0, 0);
}

// ---------------- zero fill ----------------
__global__ void k_zero(float* __restrict__ p, long n) {
    for (long i = (long)blockIdx.x * blockDim.x + threadIdx.x; i < n;
         i += (long)gridDim.x * blockDim.x)
        p[i] = 0.f;
}

// ---------------- f32 -> bf16 convert with column pad ----------------
__global__ void k_cvt(const float* __restrict__ src, u16* __restrict__ dst,
                      int R, int C, int Cp) {
    long total = (long)R * Cp;
    for (long i = (long)blockIdx.x * blockDim.x + threadIdx.x; i < total;
         i += (long)gridDim.x * blockDim.x) {
        int r = (int)(i / Cp);
        int c = (int)(i - (long)r * Cp);
        dst[i] = (c < C) ? f2bf(src[(size_t)r * C + c]) : (u16)0;
    }
}

// ---------------- fused GRU step: acc = emb[tok]@Wx^T (+ h@Wh^T), gate math ----
// Grid (64,4): bx = 64-row node tile, by = 64-col gate tile (of 256).
// Block 256 = 4 waves in 2x2; wave computes 32x32 per gate-accumulator.
// XONLY: backward single cell from h0=0 (x-part only, h' = (1-z)*n).
template<bool XONLY>
__global__ __launch_bounds__(256) void k_step(
    const int* __restrict__ tokens, int t,
    const u16* __restrict__ embbf,          // [32000][320]
    const u16* __restrict__ Wx,             // [768][320]
    const u16* __restrict__ Wh,             // [768][256]
    const float* __restrict__ bih, const float* __restrict__ bhh,
    const u16* __restrict__ hbf_in,         // [4096][256]
    const float* __restrict__ hf_in,        // [4096][256]
    float* __restrict__ outf, int ostride,
    u16* __restrict__ outbf)                // [4096][256]
{
    constexpr int NSX = DINP / 32;                    // 10
    constexpr int NS  = XONLY ? NSX : NSX + RH_ / 32; // 18

    __shared__ __align__(16) u16 As[2][64 * 32];
    __shared__ __align__(16) u16 Bs[2][3 * 64 * 32];

    const int tid = threadIdx.x;
    const int n0 = blockIdx.x * 64;
    const int c0 = blockIdx.y * 64;

    // staging mapping: thread -> (row sr, 16B chunk sq)
    const int sr = tid >> 2;
    const int sq = tid & 3;
    const int tok = tokens[(n0 + sr) * TT_ + t];
    const u16* ax  = embbf + (size_t)tok * DINP + sq * 8;
    const u16* ah  = XONLY ? ax : hbf_in + (size_t)(n0 + sr) * RH_ + sq * 8;
    const u16* bx0 = Wx + (size_t)(0 * 256 + c0 + sr) * DINP + sq * 8;
    const u16* bx1 = Wx + (size_t)(1 * 256 + c0 + sr) * DINP + sq * 8;
    const u16* bx2 = Wx + (size_t)(2 * 256 + c0 + sr) * DINP + sq * 8;
    const u16* bh0 = XONLY ? ax : Wh + (size_t)(0 * 256 + c0 + sr) * RH_ + sq * 8;
    const u16* bh1 = XONLY ? ax : Wh + (size_t)(1 * 256 + c0 + sr) * RH_ + sq * 8;
    const u16* bh2 = XONLY ? ax : Wh + (size_t)(2 * 256 + c0 + sr) * RH_ + sq * 8;

    auto STAGE = [&](int b, int s) {
        u16* da = &As[b][tid * 8];
        u16* db = &Bs[b][tid * 8];
        if (s < NSX) {
            int kk = s * 32;
            gload16(ax + kk, da);
            gload16(bx0 + kk, db);
            gload16(bx1 + kk, db + 2048);
            gload16(bx2 + kk, db + 4096);
        } else {
            int kk = (s - NSX) * 32;
            gload16(ah + kk, da);
            gload16(bh0 + kk, db);
            gload16(bh1 + kk, db + 2048);
            gload16(bh2 + kk, db + 4096);
        }
    };

    const int lane = tid & 63;
    const int wave = tid >> 6;
    const int wr = wave >> 1, wc = wave & 1;
    const int l15 = lane & 15, l4 = lane >> 4;

    f32x4 aR[2][2] = {}, aZ[2][2] = {}, aXN[2][2] = {}, aHN[2][2] = {};

    // LDS elem offsets: A row (wr*32 + fi*16 + l15), k-chunk l4*8
    const int aoff = (wr * 32 + l15) * 32 + l4 * 8;     // fi=0; +16*32 for fi=1
    const int boff = (wc * 32 + l15) * 32 + l4 * 8;     // fj=0; +512 for fj=1

    auto COMPUTE = [&](int b, bool xp) {
        bf16x8 a0 = *(const bf16x8*)&As[b][aoff];
        bf16x8 a1 = *(const bf16x8*)&As[b][aoff + 512];
        const u16* B = &Bs[b][0];
        bf16x8 r0 = *(const bf16x8*)&B[boff];
        bf16x8 r1 = *(const bf16x8*)&B[boff + 512];
        bf16x8 z0 = *(const bf16x8*)&B[2048 + boff];
        bf16x8 z1 = *(const bf16x8*)&B[2048 + boff + 512];
        bf16x8 n0f = *(const bf16x8*)&B[4096 + boff];
        bf16x8 n1f = *(const bf16x8*)&B[4096 + boff + 512];
        aR[0][0] = __builtin_amdgcn_mfma_f32_16x16x32_bf16(a0, r0, aR[0][0], 0, 0, 0);
        aR[0][1] = __builtin_amdgcn_mfma_f32_16x16x32_bf16(a0, r1, aR[0][1], 0, 0, 0);
        aR[1][0] = __builtin_amdgcn_mfma_f32_16x16x32_bf16(a1, r0, aR[1][0], 0, 0, 0);
        aR[1][1] = __builtin_amdgcn_mfma_f32_16x16x32_bf16(a1, r1, aR[1][1], 0, 0, 0);
        aZ[0][0] = __builtin_amdgcn_mfma_f32_16x16x32_bf16(a0, z0, aZ[0][0], 0, 0, 0);
        aZ[0][1] = __builtin_amdgcn_mfma_f32_16x16x32_bf16(a0, z1, aZ[0][1], 0, 0, 0);
        aZ[1][0] = __builtin_amdgcn_mfma_f32_16x16x32_bf16(a1, z0, aZ[1][0], 0, 0, 0);
        aZ[1][1] = __builtin_amdgcn_mfma_f32_16x16x32_bf16(a1, z1, aZ[1][1], 0, 0, 0);
        if (xp) {
            aXN[0][0] = __builtin_amdgcn_mfma_f32_16x16x32_bf16(a0, n0f, aXN[0][0], 0, 0, 0);
            aXN[0][1] = __builtin_amdgcn_mfma_f32_16x16x32_bf16(a0, n1f, aXN[0][1], 0, 0, 0);
            aXN[1][0] = __builtin_amdgcn_mfma_f32_16x16x32_bf16(a1, n0f, aXN[1][0], 0, 0, 0);
            aXN[1][1] = __builtin_amdgcn_mfma_f32_16x16x32_bf16(a1, n1f, aXN[1][1], 0, 0, 0);
        } else {
            aHN[0][0] = __builtin_amdgcn_mfma_f32_16x16x32_bf16(a0, n0f, aHN[0][0], 0, 0, 0);
            aHN[0][1] = __builtin_amdgcn_mfma_f32_16x16x32_bf16(a0, n1f, aHN[0][1], 0, 0, 0);
            aHN[1][0] = __builtin_amdgcn_mfma_f32_16x16x32_bf16(a1, n0f, aHN[1][0], 0, 0, 0);
            aHN[1][1] = __builtin_amdgcn_mfma_f32_16x16x32_bf16(a1, n1f, aHN[1][1], 0, 0, 0);
        }
    };

    STAGE(0, 0);
    __syncthreads();
#pragma unroll
    for (int s = 0; s < NS; ++s) {
        if (s + 1 < NS) STAGE((s + 1) & 1, s + 1);
        COMPUTE(s & 1, s < NSX);
        __syncthreads();
    }

    // epilogue: gate math. C/D layout: col = lane&15, row = (lane>>4)*4 + reg.
#pragma unroll
    for (int fj = 0; fj < 2; ++fj) {
        const int c = c0 + wc * 32 + fj * 16 + l15;   // 0..255
        const float bR  = bih[c] + bhh[c];
        const float bZ  = bih[256 + c] + bhh[256 + c];
        const float bXN = bih[512 + c];
        const float bHN = bhh[512 + c];
#pragma unroll
        for (int fi = 0; fi < 2; ++fi) {
#pragma unroll
            for (int rg = 0; rg < 4; ++rg) {
                const int n = n0 + wr * 32 + fi * 16 + l4 * 4 + rg;
                float r  = 1.f / (1.f + __expf(-(aR[fi][fj][rg] + bR)));
                float z  = 1.f / (1.f + __expf(-(aZ[fi][fj][rg] + bZ)));
                float pre = aXN[fi][fj][rg] + bXN + r * (aHN[fi][fj][rg] + bHN);
                float nv = 2.f / (1.f + __expf(-2.f * pre)) - 1.f;  // tanh
                float hp = XONLY ? 0.f : hf_in[(size_t)n * RH_ + c];
                float h  = (1.f - z) * nv + z * hp;
                outf[(size_t)n * ostride + c] = h;
                if (!XONLY) outbf[(size_t)n * RH_ + c] = f2bf(h);
            }
        }
    }
}

// ---------------- edge scatter: agg[dst] += h[src] ----------------
__global__ void k_scatter(const float* __restrict__ h, const int* __restrict__ src,
                          const int* __restrict__ dst, float* __restrict__ agg,
                          int logK, int strideH)
{
    int K = 1 << logK;
    long total = (long)EE_ << logK;
    for (long idx = (long)blockIdx.x * blockDim.x + threadIdx.x; idx < total;
         idx += (long)gridDim.x * blockDim.x) {
        int e = (int)(idx >> logK);
        int c = (int)(idx & (K - 1));
        atomicAdd(&agg[(long)dst[e] * K + c], h[(long)src[e] * strideH + c]);
    }
}

// ---------------- GCN GEMM: out = relu(A @ W + b), W is [K][256] row-major ----
__global__ __launch_bounds__(256) void k_gcn(
    const float* __restrict__ A, const float* __restrict__ W,
    const float* __restrict__ bias, float* __restrict__ out, int K)
{
    __shared__ float As[32][68];
    __shared__ float Bs[32][68];
    int tid = threadIdx.x;
    int n0 = blockIdx.x * 64, c0 = blockIdx.y * 64;
    float acc[4][4] = {};
    int tx = tid & 15, ty = tid >> 4;
    int q = tid & 7, m = tid >> 3;
    int jj = tid & 15, kr = tid >> 4;

    for (int kk = 0; kk < K; kk += 32) {
        int k4 = kk + q * 4;
        float4 av0 = *(const float4*)(A + (size_t)(n0 + m) * K + k4);
        float4 av1 = *(const float4*)(A + (size_t)(n0 + m + 32) * K + k4);
        float4 bv0 = *(const float4*)(W + (size_t)(kk + kr) * 256 + c0 + jj * 4);
        float4 bv1 = *(const float4*)(W + (size_t)(kk + kr + 16) * 256 + c0 + jj * 4);
        __syncthreads();
        int kb = q * 4;
        #pragma unroll
        for (int i = 0; i < 4; i++) {
            As[kb + i][m]      = ((const float*)&av0)[i];
            As[kb + i][m + 32] = ((const float*)&av1)[i];
        }
        *(float4*)&Bs[kr][jj * 4]      = bv0;
        *(float4*)&Bs[kr + 16][jj * 4] = bv1;
        __syncthreads();
        #pragma unroll 8
        for (int k = 0; k < 32; k++) {
            float4 a4 = *(const float4*)&As[k][ty * 4];
            float4 b4 = *(const float4*)&Bs[k][tx * 4];
            const float* ar = (const float*)&a4;
            const float* br = (const float*)&b4;
            #pragma unroll
            for (int i = 0; i < 4; i++)
                #pragma unroll
                for (int j = 0; j < 4; j++)
                    acc[i][j] = fmaf(ar[i], br[j], acc[i][j]);
        }
    }
    #pragma unroll
    for (int i = 0; i < 4; i++) {
        int n = n0 + ty * 4 + i;
        #pragma unroll
        for (int j = 0; j < 4; j++) {
            int c = c0 + tx * 4 + j;
            out[(size_t)n * 256 + c] = fmaxf(acc[i][j] + bias[c], 0.f);
        }
    }
}

// ---------------- readout ----------------
__global__ void k_readout(const float* __restrict__ h, const int* __restrict__ gid,
                          const int* __restrict__ ntype, float* __restrict__ out,
                          float* __restrict__ cnt)
{
    for (int idx = blockIdx.x * blockDim.x + threadIdx.x; idx < NN_ * 256;
         idx += gridDim.x * blockDim.x) {
        int n = idx >> 8, c = idx & 255;
        float v = h[idx];
        int g = gid[n], t = ntype[n];
        if (t == 0) {
            atomicAdd(&out[g * 256 + c], v);
            if (c == 0) atomicAdd(&cnt[g], 1.f);
        } else if (t == 1) {
            atomicAdd(&out[16384 + g * 256 + c], v);
        } else {
            atomicAdd(&out[32768 + g * 256 + c], v);
        }
    }
}

__global__ void k_finalize(float* __restrict__ out, const float* __restrict__ cnt)
{
    int idx = blockIdx.x * blockDim.x + threadIdx.x;  // < 16384
    out[idx] /= cnt[idx >> 8];
}

// ---------------- host ----------------
extern "C" void kernel_launch(void* const* d_in, const int* in_sizes, int n_in,
                              void* d_out, int out_size, void* d_ws, size_t ws_size,
                              hipStream_t stream)
{
    const int*   tokens = (const int*)d_in[0];
    const int*   esrc   = (const int*)d_in[1];
    const int*   edst   = (const int*)d_in[2];
    const int*   gid    = (const int*)d_in[3];
    const int*   ntype  = (const int*)d_in[4];
    const float* emb    = (const float*)d_in[5];
    const float* W_ih_f = (const float*)d_in[6];
    const float* W_hh_f = (const float*)d_in[7];
    const float* b_ih_f = (const float*)d_in[8];
    const float* b_hh_f = (const float*)d_in[9];
    const float* W_ih_b = (const float*)d_in[10];
    const float* b_ih_b = (const float*)d_in[12];
    const float* b_hh_b = (const float*)d_in[13];
    const float* Wg[4]  = {(const float*)d_in[14], (const float*)d_in[16],
                           (const float*)d_in[18], (const float*)d_in[20]};
    const float* bg[4]  = {(const float*)d_in[15], (const float*)d_in[17],
                           (const float*)d_in[19], (const float*)d_in[21]};
    float* out = (float*)d_out;

    // workspace layout (all 16B aligned)
    float* hfA   = (float*)d_ws;                        // [4096][256] f32
    float* hfB   = hfA + (size_t)NN_ * RH_;             // [4096][256] f32
    u16*   hbA   = (u16*)(hfB + (size_t)NN_ * RH_);     // [4096][256] bf16
    u16*   hbB   = hbA + (size_t)NN_ * RH_;
    u16*   embbf = hbB + (size_t)NN_ * RH_;             // [32000][320] bf16
    u16*   wxf   = embbf + 32000L * DINP;               // [768][320]
    u16*   whf   = wxf + (size_t)G3_ * DINP;            // [768][256]
    u16*   wxb   = whf + (size_t)G3_ * RH_;             // [768][320]
    float* HA    = (float*)(wxb + (size_t)G3_ * DINP);  // [4096][512]
    float* HB    = HA + (size_t)NN_ * 512;              // [4096][512]
    float* CNT   = HB + (size_t)NN_ * 512;              // [64]

    // one-time conversions + zero init
    k_cvt<<<2048, 256, 0, stream>>>(emb, embbf, 32000, DIN, DINP);
    k_cvt<<<256, 256, 0, stream>>>(W_ih_f, wxf, G3_, DIN, DINP);
    k_cvt<<<256, 256, 0, stream>>>(W_hh_f, whf, G3_, RH_, RH_);
    k_cvt<<<256, 256, 0, stream>>>(W_ih_b, wxb, G3_, DIN, DINP);
    k_zero<<<1024, 256, 0, stream>>>(hfA, (long)NN_ * RH_);
    k_zero<<<512, 256, 0, stream>>>((float*)hbA, (long)NN_ * RH_ / 2);

    // GRU scan (ping-pong f32+bf16 state; step 63 writes HA cols 0..255)
    float* hf[2] = {hfA, hfB};
    u16*   hb[2] = {hbA, hbB};
    for (int t = 0; t < TT_; t++) {
        int cur = t & 1, nxt = cur ^ 1;
        float* outf = (t == TT_ - 1) ? HA : hf[nxt];
        int ostride = (t == TT_ - 1) ? 512 : 256;
        k_step<false><<<dim3(64, 4), 256, 0, stream>>>(
            tokens, t, embbf, wxf, whf, b_ih_f, b_hh_f,
            hb[cur], hf[cur], outf, ostride, hb[nxt]);
    }
    // backward GRU single cell on x[:,T-1] -> HA cols 256..511
    k_step<true><<<dim3(64, 4), 256, 0, stream>>>(
        tokens, TT_ - 1, embbf, wxb, nullptr, b_ih_b, b_hh_b,
        nullptr, nullptr, HA + 256, 512, nullptr);

    // 4 GCN layers: agg in HB, output back to HA (stride 256 after layer 1)
    for (int l = 0; l < 4; l++) {
        int K = (l == 0) ? 512 : 256;
        int logK = (l == 0) ? 9 : 8;
        k_zero<<<2048, 256, 0, stream>>>(HB, (long)NN_ * K);
        k_scatter<<<4096, 256, 0, stream>>>(HA, esrc, edst, HB, logK, K);
        k_gcn<<<dim3(64, 4), 256, 0, stream>>>(HB, Wg[l], bg[l], HA, K);
    }

    // readout
    k_zero<<<256, 256, 0, stream>>>(out, 49152);
    k_zero<<<1, 64, 0, stream>>>(CNT, 64);
    k_readout<<<2048, 256, 0, stream>>>(HA, gid, ntype, out, CNT);
    k_finalize<<<64, 256, 0, stream>>>(out, CNT);
}

// Round 3
// 1012.758 us; speedup vs baseline: 5.5650x; 1.4857x over previous
//
#include <hip/hip_runtime.h>
#include <cstddef>

// Problem constants
#define NN_ 4096      // nodes
#define TT_ 64        // tokens per node
#define DIN 300       // embedding dim
#define DINP 320      // padded to mult of 32
#define RH_ 256       // rnn hidden
#define G3_ 768       // 3*RH
#define BB_ 64        // graphs
#define EE_ 65536     // edges

typedef short bf16x8 __attribute__((ext_vector_type(8)));
typedef float f32x4 __attribute__((ext_vector_type(4)));
typedef unsigned short u16;

__device__ __forceinline__ u16 f2bf(float f) {
    unsigned u = __builtin_bit_cast(unsigned, f);
    u += 0x7fff + ((u >> 16) & 1);          // RNE
    return (u16)(u >> 16);
}

__device__ __forceinline__ void gload16(const void* g, void* l) {
    __builtin_amdgcn_global_load_lds(
        (const __attribute__((address_space(1))) unsigned*)g,
        (__attribute__((address_space(3))) unsigned*)l, 16, 0, 0);
}

#define MFMA16 __builtin_amdgcn_mfma_f32_16x16x32_bf16

// ---------------- zero fill ----------------
__global__ void k_zero(float* __restrict__ p, long n) {
    for (long i = (long)blockIdx.x * blockDim.x + threadIdx.x; i < n;
         i += (long)gridDim.x * blockDim.x)
        p[i] = 0.f;
}

// ---------------- f32 -> bf16 convert with column pad ----------------
__global__ void k_cvt(const float* __restrict__ src, u16* __restrict__ dst,
                      int R, int C, int Cp) {
    long total = (long)R * Cp;
    for (long i = (long)blockIdx.x * blockDim.x + threadIdx.x; i < total;
         i += (long)gridDim.x * blockDim.x) {
        int r = (int)(i / Cp);
        int c = (int)(i - (long)r * Cp);
        dst[i] = (c < C) ? f2bf(src[(size_t)r * C + c]) : (u16)0;
    }
}

// ---------------- W [K][256] f32 -> Wt [256][K] bf16 (transpose+convert) ----
__global__ void k_cvtT(const float* __restrict__ W, u16* __restrict__ Wt, int K) {
    int total = 256 * K;
    for (int i = blockIdx.x * blockDim.x + threadIdx.x; i < total;
         i += gridDim.x * blockDim.x) {
        int c = i / K, k = i - c * K;
        Wt[i] = f2bf(W[(size_t)k * 256 + c]);
    }
}

// ---------------- build block-diagonal adjacency counts ----------------
__global__ void k_buildA(const int* __restrict__ src, const int* __restrict__ dst,
                         float* __restrict__ A) {
    int e = blockIdx.x * blockDim.x + threadIdx.x;
    if (e < EE_) {
        int g = src[e] >> 6, i = dst[e] & 63, j = src[e] & 63;
        atomicAdd(&A[(((g << 6) + i) << 6) + j], 1.f);
    }
}

// ---------------- transpose + convert: h f32 [4096][C] -> hT bf16 [C][4096] --
__global__ __launch_bounds__(256) void k_trans(const float* __restrict__ h, int C,
                                               u16* __restrict__ hT) {
    __shared__ u16 Ls[64][72];
    int r0 = blockIdx.x * 64, c0 = blockIdx.y * 64;
    int tid = threadIdx.x;
    int r = tid >> 2, cq = tid & 3;
#pragma unroll
    for (int i = 0; i < 4; i++) {
        float4 v = *(const float4*)(h + (size_t)(r0 + r) * C + c0 + cq * 16 + i * 4);
        Ls[r][cq * 16 + i * 4 + 0] = f2bf(v.x);
        Ls[r][cq * 16 + i * 4 + 1] = f2bf(v.y);
        Ls[r][cq * 16 + i * 4 + 2] = f2bf(v.z);
        Ls[r][cq * 16 + i * 4 + 3] = f2bf(v.w);
    }
    __syncthreads();
    int c = tid >> 2, rq = tid & 3;
    u16 tmp[16];
#pragma unroll
    for (int i = 0; i < 16; i++) tmp[i] = Ls[rq * 16 + i][c];
    u16* o = hT + (size_t)(c0 + c) * NN_ + r0 + rq * 16;
    *(uint4*)o = ((const uint4*)tmp)[0];
    *(uint4*)(o + 8) = ((const uint4*)tmp)[1];
}

// ---------------- fused GRU step (BM=32): grid (128,4), 2 blocks/CU ----------
template<bool XONLY>
__global__ __launch_bounds__(256) void k_step(
    const int* __restrict__ tokens, int t,
    const u16* __restrict__ embbf,          // [32000][320]
    const u16* __restrict__ Wx,             // [768][320]
    const u16* __restrict__ Wh,             // [768][256]
    const float* __restrict__ bih, const float* __restrict__ bhh,
    const u16* __restrict__ hbf_in,         // [4096][256]
    const float* __restrict__ hf_in,        // [4096][256]
    float* __restrict__ outf, int ostride,
    u16* __restrict__ outbf)                // [4096][256]
{
    constexpr int NSX = DINP / 32;                    // 10
    constexpr int NS  = XONLY ? NSX : NSX + RH_ / 32; // 18

    __shared__ __align__(16) u16 As[2][32 * 32];
    __shared__ __align__(16) u16 Bs[2][3 * 64 * 32];

    const int tid = threadIdx.x;
    const int n0 = blockIdx.x * 32;
    const int c0 = blockIdx.y * 64;

    const int sr = tid >> 2;        // B row 0..63 (A row 0..31 for tid<128)
    const int sq = tid & 3;
    const int tok = (tid < 128) ? tokens[(n0 + sr) * TT_ + t] : 0;
    const u16* ax  = embbf + (size_t)tok * DINP + sq * 8;
    const u16* ah  = XONLY ? ax : hbf_in + (size_t)(n0 + sr) * RH_ + sq * 8;
    const u16* bx0 = Wx + (size_t)(0 * 256 + c0 + sr) * DINP + sq * 8;
    const u16* bx1 = Wx + (size_t)(1 * 256 + c0 + sr) * DINP + sq * 8;
    const u16* bx2 = Wx + (size_t)(2 * 256 + c0 + sr) * DINP + sq * 8;
    const u16* bh0 = XONLY ? ax : Wh + (size_t)(0 * 256 + c0 + sr) * RH_ + sq * 8;
    const u16* bh1 = XONLY ? ax : Wh + (size_t)(1 * 256 + c0 + sr) * RH_ + sq * 8;
    const u16* bh2 = XONLY ? ax : Wh + (size_t)(2 * 256 + c0 + sr) * RH_ + sq * 8;

    auto STAGE = [&](int b, int s) {
        u16* db = &Bs[b][tid * 8];
        if (s < NSX) {
            int kk = s * 32;
            if (tid < 128) gload16(ax + kk, &As[b][tid * 8]);
            gload16(bx0 + kk, db);
            gload16(bx1 + kk, db + 2048);
            gload16(bx2 + kk, db + 4096);
        } else {
            int kk = (s - NSX) * 32;
            if (tid < 128) gload16(ah + kk, &As[b][tid * 8]);
            gload16(bh0 + kk, db);
            gload16(bh1 + kk, db + 2048);
            gload16(bh2 + kk, db + 4096);
        }
    };

    const int lane = tid & 63;
    const int wave = tid >> 6;
    const int wr = wave >> 1, wc = wave & 1;   // wave tile: 16 rows x 32 cols
    const int l15 = lane & 15, l4 = lane >> 4;

    f32x4 aR[2] = {}, aZ[2] = {}, aXN[2] = {}, aHN[2] = {};

    const int aoff = (wr * 16 + l15) * 32 + l4 * 8;
    const int boff = (wc * 32 + l15) * 32 + l4 * 8;     // fj=0; +512 for fj=1

    auto COMPUTE = [&](int b, bool xp) {
        bf16x8 a0 = *(const bf16x8*)&As[b][aoff];
        const u16* B = &Bs[b][0];
        bf16x8 r0 = *(const bf16x8*)&B[boff];
        bf16x8 r1 = *(const bf16x8*)&B[boff + 512];
        bf16x8 z0 = *(const bf16x8*)&B[2048 + boff];
        bf16x8 z1 = *(const bf16x8*)&B[2048 + boff + 512];
        bf16x8 n0f = *(const bf16x8*)&B[4096 + boff];
        bf16x8 n1f = *(const bf16x8*)&B[4096 + boff + 512];
        aR[0] = MFMA16(a0, r0, aR[0], 0, 0, 0);
        aR[1] = MFMA16(a0, r1, aR[1], 0, 0, 0);
        aZ[0] = MFMA16(a0, z0, aZ[0], 0, 0, 0);
        aZ[1] = MFMA16(a0, z1, aZ[1], 0, 0, 0);
        if (xp) {
            aXN[0] = MFMA16(a0, n0f, aXN[0], 0, 0, 0);
            aXN[1] = MFMA16(a0, n1f, aXN[1], 0, 0, 0);
        } else {
            aHN[0] = MFMA16(a0, n0f, aHN[0], 0, 0, 0);
            aHN[1] = MFMA16(a0, n1f, aHN[1], 0, 0, 0);
        }
    };

    STAGE(0, 0);
    __syncthreads();
#pragma unroll
    for (int s = 0; s < NS; ++s) {
        if (s + 1 < NS) STAGE((s + 1) & 1, s + 1);
        COMPUTE(s & 1, s < NSX);
        __syncthreads();
    }

    // epilogue: C/D layout col=lane&15, row=(lane>>4)*4+reg
#pragma unroll
    for (int fj = 0; fj < 2; ++fj) {
        const int c = c0 + wc * 32 + fj * 16 + l15;   // 0..255
        const float bR  = bih[c] + bhh[c];
        const float bZ  = bih[256 + c] + bhh[256 + c];
        const float bXN = bih[512 + c];
        const float bHN = bhh[512 + c];
#pragma unroll
        for (int rg = 0; rg < 4; ++rg) {
            const int n = n0 + wr * 16 + l4 * 4 + rg;
            float r  = 1.f / (1.f + __expf(-(aR[fj][rg] + bR)));
            float z  = 1.f / (1.f + __expf(-(aZ[fj][rg] + bZ)));
            float pre = aXN[fj][rg] + bXN + r * (aHN[fj][rg] + bHN);
            float nv = 2.f / (1.f + __expf(-2.f * pre)) - 1.f;  // tanh
            float hp = XONLY ? 0.f : hf_in[(size_t)n * RH_ + c];
            float h  = (1.f - z) * nv + z * hp;
            outf[(size_t)n * ostride + c] = h;
            if (!XONLY) outbf[(size_t)n * RH_ + c] = f2bf(h);
        }
    }
}

// ---------------- block-diag aggregation: agg_g = A_g @ h_g (bf16 MFMA) -----
// grid (64 graphs, C/64). All operands straight from L2 (tiny).
__global__ __launch_bounds__(256) void k_agg(
    const u16* __restrict__ Abf,            // [64][64][64]
    const u16* __restrict__ hT,             // [C][4096]
    u16* __restrict__ aggbf, int C)         // [4096][C]
{
    const int g = blockIdx.x, ct = blockIdx.y;
    const int lane = threadIdx.x & 63, wave = threadIdx.x >> 6;
    const int wi = wave >> 1, wcC = wave & 1;
    const int l15 = lane & 15, l4 = lane >> 4;
    f32x4 acc[2][2] = {};
#pragma unroll
    for (int kc = 0; kc < 2; kc++) {
        bf16x8 af[2], bf_[2];
#pragma unroll
        for (int fi = 0; fi < 2; fi++)
            af[fi] = *(const bf16x8*)(Abf + ((size_t)g * 64 + wi * 32 + fi * 16 + l15) * 64
                                      + kc * 32 + l4 * 8);
#pragma unroll
        for (int fj = 0; fj < 2; fj++)
            bf_[fj] = *(const bf16x8*)(hT + (size_t)(ct * 64 + wcC * 32 + fj * 16 + l15) * NN_
                                       + g * 64 + kc * 32 + l4 * 8);
#pragma unroll
        for (int fi = 0; fi < 2; fi++)
#pragma unroll
            for (int fj = 0; fj < 2; fj++)
                acc[fi][fj] = MFMA16(af[fi], bf_[fj], acc[fi][fj], 0, 0, 0);
    }
#pragma unroll
    for (int fi = 0; fi < 2; fi++)
#pragma unroll
        for (int fj = 0; fj < 2; fj++)
#pragma unroll
            for (int rg = 0; rg < 4; rg++) {
                int n = g * 64 + wi * 32 + fi * 16 + l4 * 4 + rg;
                int c = ct * 64 + wcC * 32 + fj * 16 + l15;
                aggbf[(size_t)n * C + c] = f2bf(acc[fi][fj][rg]);
            }
}

// ---------------- GCN GEMM (bf16 MFMA): out = relu(agg @ W + b) -------------
template<int K>
__global__ __launch_bounds__(256) void k_gcnM(
    const u16* __restrict__ Ag,             // [4096][K] bf16
    const u16* __restrict__ Wt,             // [256][K]  bf16 (W transposed)
    const float* __restrict__ bias,
    float* __restrict__ outF)               // [4096][256] f32
{
    __shared__ __align__(16) u16 As[2][64 * 32];
    __shared__ __align__(16) u16 Bs[2][64 * 32];
    const int tid = threadIdx.x;
    const int n0 = blockIdx.x * 64, c0 = blockIdx.y * 64;
    const int sr = tid >> 2, sq = tid & 3;
    const u16* pa = Ag + (size_t)(n0 + sr) * K + sq * 8;
    const u16* pb = Wt + (size_t)(c0 + sr) * K + sq * 8;

    const int lane = tid & 63, wave = tid >> 6;
    const int wr = wave >> 1, wc = wave & 1;
    const int l15 = lane & 15, l4 = lane >> 4;
    const int aoff = (wr * 32 + l15) * 32 + l4 * 8;
    const int boff = (wc * 32 + l15) * 32 + l4 * 8;
    f32x4 acc[2][2] = {};

    gload16(pa, &As[0][tid * 8]);
    gload16(pb, &Bs[0][tid * 8]);
    __syncthreads();
    constexpr int NSK = K / 32;
#pragma unroll
    for (int s = 0; s < NSK; s++) {
        if (s + 1 < NSK) {
            gload16(pa + (s + 1) * 32, &As[(s + 1) & 1][tid * 8]);
            gload16(pb + (s + 1) * 32, &Bs[(s + 1) & 1][tid * 8]);
        }
        const int b = s & 1;
        bf16x8 a0 = *(const bf16x8*)&As[b][aoff];
        bf16x8 a1 = *(const bf16x8*)&As[b][aoff + 512];
        bf16x8 b0 = *(const bf16x8*)&Bs[b][boff];
        bf16x8 b1 = *(const bf16x8*)&Bs[b][boff + 512];
        acc[0][0] = MFMA16(a0, b0, acc[0][0], 0, 0, 0);
        acc[0][1] = MFMA16(a0, b1, acc[0][1], 0, 0, 0);
        acc[1][0] = MFMA16(a1, b0, acc[1][0], 0, 0, 0);
        acc[1][1] = MFMA16(a1, b1, acc[1][1], 0, 0, 0);
        __syncthreads();
    }
#pragma unroll
    for (int fj = 0; fj < 2; fj++) {
        const int c = c0 + wc * 32 + fj * 16 + l15;
        const float bb = bias[c];
#pragma unroll
        for (int fi = 0; fi < 2; fi++)
#pragma unroll
            for (int rg = 0; rg < 4; rg++) {
                const int n = n0 + wr * 32 + fi * 16 + l4 * 4 + rg;
                outF[(size_t)n * 256 + c] = fmaxf(acc[fi][fj][rg] + bb, 0.f);
            }
    }
}

// ---------------- readout ----------------
__global__ void k_readout(const float* __restrict__ h, const int* __restrict__ gid,
                          const int* __restrict__ ntype, float* __restrict__ out,
                          float* __restrict__ cnt)
{
    for (int idx = blockIdx.x * blockDim.x + threadIdx.x; idx < NN_ * 256;
         idx += gridDim.x * blockDim.x) {
        int n = idx >> 8, c = idx & 255;
        float v = h[idx];
        int g = gid[n], t = ntype[n];
        if (t == 0) {
            atomicAdd(&out[g * 256 + c], v);
            if (c == 0) atomicAdd(&cnt[g], 1.f);
        } else if (t == 1) {
            atomicAdd(&out[16384 + g * 256 + c], v);
        } else {
            atomicAdd(&out[32768 + g * 256 + c], v);
        }
    }
}

__global__ void k_finalize(float* __restrict__ out, const float* __restrict__ cnt)
{
    int idx = blockIdx.x * blockDim.x + threadIdx.x;  // < 16384
    out[idx] /= cnt[idx >> 8];
}

// ---------------- host ----------------
extern "C" void kernel_launch(void* const* d_in, const int* in_sizes, int n_in,
                              void* d_out, int out_size, void* d_ws, size_t ws_size,
                              hipStream_t stream)
{
    const int*   tokens = (const int*)d_in[0];
    const int*   esrc   = (const int*)d_in[1];
    const int*   edst   = (const int*)d_in[2];
    const int*   gid    = (const int*)d_in[3];
    const int*   ntype  = (const int*)d_in[4];
    const float* emb    = (const float*)d_in[5];
    const float* W_ih_f = (const float*)d_in[6];
    const float* W_hh_f = (const float*)d_in[7];
    const float* b_ih_f = (const float*)d_in[8];
    const float* b_hh_f = (const float*)d_in[9];
    const float* W_ih_b = (const float*)d_in[10];
    const float* b_ih_b = (const float*)d_in[12];
    const float* b_hh_b = (const float*)d_in[13];
    const float* Wg[4]  = {(const float*)d_in[14], (const float*)d_in[16],
                           (const float*)d_in[18], (const float*)d_in[20]};
    const float* bg[4]  = {(const float*)d_in[15], (const float*)d_in[17],
                           (const float*)d_in[19], (const float*)d_in[21]};
    float* out = (float*)d_out;

    // workspace layout (f32-unit offsets; all 16B aligned)
    float* hfA   = (float*)d_ws;                        // [4096][256] f32
    float* hfB   = hfA + (size_t)NN_ * RH_;             // [4096][256] f32
    u16*   hbA   = (u16*)(hfB + (size_t)NN_ * RH_);     // [4096][256] bf16
    u16*   hbB   = hbA + (size_t)NN_ * RH_;
    u16*   embbf = hbB + (size_t)NN_ * RH_;             // [32000][320]
    u16*   wxf   = embbf + 32000L * DINP;               // [768][320]
    u16*   whf   = wxf + (size_t)G3_ * DINP;            // [768][256]
    u16*   wxb   = whf + (size_t)G3_ * RH_;             // [768][320]
    u16*   wtg   = wxb + (size_t)G3_ * DINP;            // [256][512] max
    u16*   Abf   = wtg + 256L * 512;                    // [64][64][64]
    u16*   hT    = Abf + 64L * 64 * 64;                 // [512][4096] max
    u16*   aggb  = hT + 512L * NN_;                     // [4096][512] max
    float* Af    = (float*)(aggb + (size_t)NN_ * 512);  // [64][64][64] f32
    float* HA    = Af + 64L * 64 * 64;                  // [4096][512] f32
    float* CNT   = HA + (size_t)NN_ * 512;              // [64]
    float* hF    = hfA;                                 // reuse after scan

    // one-time conversions + zero init + adjacency build
    k_cvt<<<2048, 256, 0, stream>>>(emb, embbf, 32000, DIN, DINP);
    k_cvt<<<256, 256, 0, stream>>>(W_ih_f, wxf, G3_, DIN, DINP);
    k_cvt<<<256, 256, 0, stream>>>(W_hh_f, whf, G3_, RH_, RH_);
    k_cvt<<<256, 256, 0, stream>>>(W_ih_b, wxb, G3_, DIN, DINP);
    k_zero<<<1024, 256, 0, stream>>>(hfA, (long)NN_ * RH_);
    k_zero<<<512, 256, 0, stream>>>((float*)hbA, (long)NN_ * RH_ / 2);
    k_zero<<<256, 256, 0, stream>>>(Af, 64L * 64 * 64);
    k_buildA<<<256, 256, 0, stream>>>(esrc, edst, Af);
    k_cvt<<<256, 256, 0, stream>>>(Af, Abf, 64 * 64, 64, 64);

    // GRU scan (grid 128x4, 2 blocks/CU); step 63 writes HA cols 0..255
    float* hf[2] = {hfA, hfB};
    u16*   hb[2] = {hbA, hbB};
    for (int t = 0; t < TT_; t++) {
        int cur = t & 1, nxt = cur ^ 1;
        float* outf = (t == TT_ - 1) ? HA : hf[nxt];
        int ostride = (t == TT_ - 1) ? 512 : 256;
        k_step<false><<<dim3(128, 4), 256, 0, stream>>>(
            tokens, t, embbf, wxf, whf, b_ih_f, b_hh_f,
            hb[cur], hf[cur], outf, ostride, hb[nxt]);
    }
    // backward GRU single cell on x[:,T-1] -> HA cols 256..511
    k_step<true><<<dim3(128, 4), 256, 0, stream>>>(
        tokens, TT_ - 1, embbf, wxb, nullptr, b_ih_b, b_hh_b,
        nullptr, nullptr, HA + 256, 512, nullptr);

    // GCN: hT <- transpose(h); agg <- blockdiag(A) @ h; h <- relu(agg @ W + b)
    k_trans<<<dim3(64, 8), 256, 0, stream>>>(HA, 512, hT);
    for (int l = 0; l < 4; l++) {
        int K = (l == 0) ? 512 : 256;
        k_cvtT<<<128, 256, 0, stream>>>(Wg[l], wtg, K);
        k_agg<<<dim3(64, K / 64), 256, 0, stream>>>(Abf, hT, aggb, K);
        if (K == 512)
            k_gcnM<512><<<dim3(64, 4), 256, 0, stream>>>(aggb, wtg, bg[l], hF);
        else
            k_gcnM<256><<<dim3(64, 4), 256, 0, stream>>>(aggb, wtg, bg[l], hF);
        if (l < 3) k_trans<<<dim3(64, 4), 256, 0, stream>>>(hF, 256, hT);
    }

    // readout
    k_zero<<<256, 256, 0, stream>>>(out, 49152);
    k_zero<<<1, 64, 0, stream>>>(CNT, 64);
    k_readout<<<2048, 256, 0, stream>>>(hF, gid, ntype, out, CNT);
    k_finalize<<<64, 256, 0, stream>>>(out, CNT);
}

// Round 5
// 399.988 us; speedup vs baseline: 14.0905x; 2.5320x over previous
//
#include <hip/hip_runtime.h>
#include <cstddef>

// Problem constants
#define NN_ 4096      // nodes
#define TT_ 64        // tokens per node
#define DIN 300       // embedding dim
#define DINP 320      // padded to mult of 32
#define RH_ 256       // rnn hidden
#define G3_ 768       // 3*RH
#define BB_ 64        // graphs
#define EE_ 65536     // edges

typedef short bf16x8 __attribute__((ext_vector_type(8)));
typedef float f32x4 __attribute__((ext_vector_type(4)));
typedef unsigned short u16;

__device__ __forceinline__ u16 f2bf(float f) {
    unsigned u = __builtin_bit_cast(unsigned, f);
    u += 0x7fff + ((u >> 16) & 1);          // RNE
    return (u16)(u >> 16);
}
__device__ __forceinline__ float bf2f(u16 v) {
    return __builtin_bit_cast(float, (unsigned)v << 16);
}

__device__ __forceinline__ void gload16(const void* g, void* l) {
    __builtin_amdgcn_global_load_lds(
        (const __attribute__((address_space(1))) unsigned*)g,
        (__attribute__((address_space(3))) unsigned*)l, 16, 0, 0);
}

#define MFMA16 __builtin_amdgcn_mfma_f32_16x16x32_bf16

// ---------------- zero fill ----------------
__global__ void k_zero(float* __restrict__ p, long n) {
    for (long i = (long)blockIdx.x * blockDim.x + threadIdx.x; i < n;
         i += (long)gridDim.x * blockDim.x)
        p[i] = 0.f;
}

// ---------------- f32 -> bf16 convert with column pad ----------------
__global__ void k_cvt(const float* __restrict__ src, u16* __restrict__ dst,
                      int R, int C, int Cp) {
    long total = (long)R * Cp;
    for (long i = (long)blockIdx.x * blockDim.x + threadIdx.x; i < total;
         i += (long)gridDim.x * blockDim.x) {
        int r = (int)(i / Cp);
        int c = (int)(i - (long)r * Cp);
        dst[i] = (c < C) ? f2bf(src[(size_t)r * C + c]) : (u16)0;
    }
}

// ---------------- W [K][256] f32 -> Wt [256][K] bf16 (transpose+convert) ----
__global__ void k_cvtT(const float* __restrict__ W, u16* __restrict__ Wt, int K) {
    int total = 256 * K;
    for (int i = blockIdx.x * blockDim.x + threadIdx.x; i < total;
         i += gridDim.x * blockDim.x) {
        int c = i / K, k = i - c * K;
        Wt[i] = f2bf(W[(size_t)k * 256 + c]);
    }
}

// ---------------- build block-diagonal adjacency counts ----------------
__global__ void k_buildA(const int* __restrict__ src, const int* __restrict__ dst,
                         float* __restrict__ A) {
    int e = blockIdx.x * blockDim.x + threadIdx.x;
    if (e < EE_) {
        int g = src[e] >> 6, i = dst[e] & 63, j = src[e] & 63;
        atomicAdd(&A[(((g << 6) + i) << 6) + j], 1.f);
    }
}

// ---------------- transpose + convert: h f32 [4096][C] -> hT bf16 [C][4096] --
__global__ __launch_bounds__(256) void k_trans(const float* __restrict__ h, int C,
                                               u16* __restrict__ hT) {
    __shared__ u16 Ls[64][72];
    int r0 = blockIdx.x * 64, c0 = blockIdx.y * 64;
    int tid = threadIdx.x;
    int r = tid >> 2, cq = tid & 3;
#pragma unroll
    for (int i = 0; i < 4; i++) {
        float4 v = *(const float4*)(h + (size_t)(r0 + r) * C + c0 + cq * 16 + i * 4);
        Ls[r][cq * 16 + i * 4 + 0] = f2bf(v.x);
        Ls[r][cq * 16 + i * 4 + 1] = f2bf(v.y);
        Ls[r][cq * 16 + i * 4 + 2] = f2bf(v.z);
        Ls[r][cq * 16 + i * 4 + 3] = f2bf(v.w);
    }
    __syncthreads();
    int c = tid >> 2, rq = tid & 3;
    u16 tmp[16];
#pragma unroll
    for (int i = 0; i < 16; i++) tmp[i] = Ls[rq * 16 + i][c];
    u16* o = hT + (size_t)(c0 + c) * NN_ + r0 + rq * 16;
    *(uint4*)o = ((const uint4*)tmp)[0];
    *(uint4*)(o + 8) = ((const uint4*)tmp)[1];
}

// ---------------- XPROJ = emb @ Wx^T + bih (+bhh for r,z cols) -> bf16 ------
// [32000][320] @ [768][320]^T -> [32000][768]. Grid (500, 12), BM=BN=64.
__global__ __launch_bounds__(256) void k_xproj(
    const u16* __restrict__ embbf, const u16* __restrict__ Wx,
    const float* __restrict__ bih, const float* __restrict__ bhh,
    u16* __restrict__ XP)
{
    __shared__ __align__(16) u16 As[2][64 * 32];
    __shared__ __align__(16) u16 Bs[2][64 * 32];
    const int tid = threadIdx.x;
    const int v0 = blockIdx.x * 64, c0 = blockIdx.y * 64;
    const int sr = tid >> 2, sq = tid & 3;
    const u16* pa = embbf + (size_t)(v0 + sr) * DINP + sq * 8;
    const u16* pb = Wx + (size_t)(c0 + sr) * DINP + sq * 8;

    const int lane = tid & 63, wave = tid >> 6;
    const int wr = wave >> 1, wc = wave & 1;
    const int l15 = lane & 15, l4 = lane >> 4;
    const int aoff = (wr * 32 + l15) * 32 + l4 * 8;
    const int boff = (wc * 32 + l15) * 32 + l4 * 8;
    f32x4 acc[2][2] = {};

    gload16(pa, &As[0][tid * 8]);
    gload16(pb, &Bs[0][tid * 8]);
    __syncthreads();
    constexpr int NSK = DINP / 32;   // 10
#pragma unroll
    for (int s = 0; s < NSK; s++) {
        if (s + 1 < NSK) {
            gload16(pa + (s + 1) * 32, &As[(s + 1) & 1][tid * 8]);
            gload16(pb + (s + 1) * 32, &Bs[(s + 1) & 1][tid * 8]);
        }
        const int b = s & 1;
        bf16x8 a0 = *(const bf16x8*)&As[b][aoff];
        bf16x8 a1 = *(const bf16x8*)&As[b][aoff + 512];
        bf16x8 b0 = *(const bf16x8*)&Bs[b][boff];
        bf16x8 b1 = *(const bf16x8*)&Bs[b][boff + 512];
        acc[0][0] = MFMA16(a0, b0, acc[0][0], 0, 0, 0);
        acc[0][1] = MFMA16(a0, b1, acc[0][1], 0, 0, 0);
        acc[1][0] = MFMA16(a1, b0, acc[1][0], 0, 0, 0);
        acc[1][1] = MFMA16(a1, b1, acc[1][1], 0, 0, 0);
        __syncthreads();
    }
#pragma unroll
    for (int fj = 0; fj < 2; fj++) {
        const int c = c0 + wc * 32 + fj * 16 + l15;   // 0..767
        const float bb = bih[c] + (c < 512 ? bhh[c] : 0.f);
#pragma unroll
        for (int fi = 0; fi < 2; fi++)
#pragma unroll
            for (int rg = 0; rg < 4; rg++) {
                const int v = v0 + wr * 32 + fi * 16 + l4 * 4 + rg;
                XP[(size_t)v * G3_ + c] = f2bf(acc[fi][fj][rg] + bb);
            }
    }
}

// ---------------- persistent GRU scan: 64 steps in one kernel ---------------
// 256 blocks x 512 threads (8 waves). Block owns 16 nodes for all T steps.
// Wh resident in VGPRs (wave w handles gate-cols [w*32,(w+1)*32) x 3 gates).
// h carried in f32 regs (lane-stationary) + bf16 in swizzled LDS for A-frags.
// XP rows for step t+1 staged to LDS via global_load_lds during step t.
__global__ __launch_bounds__(512, 2) void k_scan(
    const int* __restrict__ tokens,      // [4096][64]
    const u16* __restrict__ XPROJ,       // [32000][768]
    const u16* __restrict__ Wh,          // [768][256]
    const float* __restrict__ bhh,       // b_hh_f (n-gate part used)
    float* __restrict__ HA)              // [4096][512], writes cols 0..255
{
    __shared__ __align__(16) u16 XPs[16 * G3_];   // 24 KB
    __shared__ __align__(16) u16 hS[16 * RH_];    // 8 KB, swizzled
    __shared__ int toks[16 * TT_];                // 4 KB, [row][t]

    const int tid = threadIdx.x;
    const int n0 = blockIdx.x * 16;
    const int lane = tid & 63, wave = tid >> 6;
    const int l15 = lane & 15, l4 = lane >> 4;
    const int c0w = wave * 32;

    // prologue: tokens -> LDS ; zero hS
    toks[tid] = tokens[n0 * TT_ + tid];
    toks[512 + tid] = tokens[n0 * TT_ + 512 + tid];
    ((unsigned long long*)hS)[tid] = 0ull;
    ((unsigned long long*)hS)[512 + tid] = 0ull;

    // Wh -> registers: 3 gates x 2 col-frags x 8 k-chunks (192 VGPR)
    bf16x8 Bv[3][2][8];
#pragma unroll
    for (int g = 0; g < 3; ++g)
#pragma unroll
        for (int f = 0; f < 2; ++f)
#pragma unroll
            for (int ks = 0; ks < 8; ++ks)
                Bv[g][f][ks] = *(const bf16x8*)(
                    Wh + (size_t)(g * 256 + c0w + f * 16 + l15) * RH_ + ks * 32 + l4 * 8);

    const float bhn0 = bhh[512 + c0w + l15];
    const float bhn1 = bhh[512 + c0w + 16 + l15];

    // XP staging map (t-invariant): chunk c = tid + i*512, row = c/96
    int srow[3], soff[3];
#pragma unroll
    for (int i = 0; i < 3; ++i) {
        int c = tid + i * 512;
        srow[i] = c / 96;
        soff[i] = (c - srow[i] * 96) * 8;     // u16 units within row
    }
    u16* sdst[3];
#pragma unroll
    for (int i = 0; i < 3; ++i) sdst[i] = XPs + (tid + i * 512) * 8;

    auto STAGE_XP = [&](int t) {
#pragma unroll
        for (int i = 0; i < 3; ++i) {
            int tok = toks[srow[i] * TT_ + t];
            gload16(XPROJ + (size_t)tok * G3_ + soff[i], sdst[i]);
        }
    };

    f32x4 hprev0 = {0.f, 0.f, 0.f, 0.f}, hprev1 = {0.f, 0.f, 0.f, 0.f};

    __syncthreads();   // toks/hS LDS writes visible to ALL waves (prologue race fix)

    STAGE_XP(0);
    __syncthreads();

    for (int t = 0; t < TT_; ++t) {
        // ---- recurrent GEMM: gh = h @ Wh^T (A from swizzled hS) ----
        f32x4 acc[3][2] = {};
#pragma unroll
        for (int ks = 0; ks < 8; ++ks) {
            const int aa = (l15 * 512 + ks * 64 + l4 * 16) ^ ((l15 & 7) << 4);
            bf16x8 a = *(const bf16x8*)((const char*)hS + aa);
#pragma unroll
            for (int g = 0; g < 3; ++g) {
                acc[g][0] = MFMA16(a, Bv[g][0][ks], acc[g][0], 0, 0, 0);
                acc[g][1] = MFMA16(a, Bv[g][1][ks], acc[g][1], 0, 0, 0);
            }
        }
        __syncthreads();   // hS reads done; XP DMA for step t drained+visible

        // ---- gate math (XP from LDS; r/z biases baked into XPROJ) ----
#pragma unroll
        for (int f = 0; f < 2; ++f) {
            const int cc = c0w + f * 16 + l15;     // 0..255
            const float bhn = f == 0 ? bhn0 : bhn1;
#pragma unroll
            for (int rg = 0; rg < 4; ++rg) {
                const int r = l4 * 4 + rg;
                const int xb = r * G3_ + cc;
                float xr = bf2f(XPs[xb]);
                float xz = bf2f(XPs[xb + 256]);
                float xn = bf2f(XPs[xb + 512]);
                float gr = f == 0 ? acc[0][0][rg] : acc[0][1][rg];
                float gz = f == 0 ? acc[1][0][rg] : acc[1][1][rg];
                float gn = f == 0 ? acc[2][0][rg] : acc[2][1][rg];
                float hp = f == 0 ? hprev0[rg] : hprev1[rg];
                float rr = 1.f / (1.f + __expf(-(xr + gr)));
                float zz = 1.f / (1.f + __expf(-(xz + gz)));
                float pre = xn + rr * (gn + bhn);
                float nv = 2.f / (1.f + __expf(-2.f * pre)) - 1.f;
                float hnew = (1.f - zz) * nv + zz * hp;
                if (f == 0) hprev0[rg] = hnew; else hprev1[rg] = hnew;
                if (t < TT_ - 1) {
                    const int ba = (r * 512 + cc * 2) ^ ((r & 7) << 4);
                    *(u16*)((char*)hS + ba) = f2bf(hnew);
                } else {
                    HA[(size_t)(n0 + r) * 512 + cc] = hnew;
                }
            }
        }
        __syncthreads();   // XPs reads done; hS writes visible
        if (t < TT_ - 1) STAGE_XP(t + 1);
    }
}

// ---------------- backward GRU single cell (x-part only, h0=0) --------------
template<bool XONLY>
__global__ __launch_bounds__(256) void k_step(
    const int* __restrict__ tokens, int t,
    const u16* __restrict__ embbf, const u16* __restrict__ Wx,
    const u16* __restrict__ Wh,
    const float* __restrict__ bih, const float* __restrict__ bhh,
    const u16* __restrict__ hbf_in, const float* __restrict__ hf_in,
    float* __restrict__ outf, int ostride, u16* __restrict__ outbf)
{
    constexpr int NSX = DINP / 32;
    constexpr int NS  = XONLY ? NSX : NSX + RH_ / 32;

    __shared__ __align__(16) u16 As[2][32 * 32];
    __shared__ __align__(16) u16 Bs[2][3 * 64 * 32];

    const int tid = threadIdx.x;
    const int n0 = blockIdx.x * 32;
    const int c0 = blockIdx.y * 64;

    const int sr = tid >> 2;
    const int sq = tid & 3;
    const int tok = (tid < 128) ? tokens[(n0 + sr) * TT_ + t] : 0;
    const u16* ax  = embbf + (size_t)tok * DINP + sq * 8;
    const u16* ah  = XONLY ? ax : hbf_in + (size_t)(n0 + sr) * RH_ + sq * 8;
    const u16* bx0 = Wx + (size_t)(0 * 256 + c0 + sr) * DINP + sq * 8;
    const u16* bx1 = Wx + (size_t)(1 * 256 + c0 + sr) * DINP + sq * 8;
    const u16* bx2 = Wx + (size_t)(2 * 256 + c0 + sr) * DINP + sq * 8;
    const u16* bh0 = XONLY ? ax : Wh + (size_t)(0 * 256 + c0 + sr) * RH_ + sq * 8;
    const u16* bh1 = XONLY ? ax : Wh + (size_t)(1 * 256 + c0 + sr) * RH_ + sq * 8;
    const u16* bh2 = XONLY ? ax : Wh + (size_t)(2 * 256 + c0 + sr) * RH_ + sq * 8;

    auto STAGE = [&](int b, int s) {
        u16* db = &Bs[b][tid * 8];
        if (s < NSX) {
            int kk = s * 32;
            if (tid < 128) gload16(ax + kk, &As[b][tid * 8]);
            gload16(bx0 + kk, db);
            gload16(bx1 + kk, db + 2048);
            gload16(bx2 + kk, db + 4096);
        } else {
            int kk = (s - NSX) * 32;
            if (tid < 128) gload16(ah + kk, &As[b][tid * 8]);
            gload16(bh0 + kk, db);
            gload16(bh1 + kk, db + 2048);
            gload16(bh2 + kk, db + 4096);
        }
    };

    const int lane = tid & 63;
    const int wave = tid >> 6;
    const int wr = wave >> 1, wc = wave & 1;
    const int l15 = lane & 15, l4 = lane >> 4;

    f32x4 aR[2] = {}, aZ[2] = {}, aXN[2] = {}, aHN[2] = {};

    const int aoff = (wr * 16 + l15) * 32 + l4 * 8;
    const int boff = (wc * 32 + l15) * 32 + l4 * 8;

    auto COMPUTE = [&](int b, bool xp) {
        bf16x8 a0 = *(const bf16x8*)&As[b][aoff];
        const u16* B = &Bs[b][0];
        bf16x8 r0 = *(const bf16x8*)&B[boff];
        bf16x8 r1 = *(const bf16x8*)&B[boff + 512];
        bf16x8 z0 = *(const bf16x8*)&B[2048 + boff];
        bf16x8 z1 = *(const bf16x8*)&B[2048 + boff + 512];
        bf16x8 n0f = *(const bf16x8*)&B[4096 + boff];
        bf16x8 n1f = *(const bf16x8*)&B[4096 + boff + 512];
        aR[0] = MFMA16(a0, r0, aR[0], 0, 0, 0);
        aR[1] = MFMA16(a0, r1, aR[1], 0, 0, 0);
        aZ[0] = MFMA16(a0, z0, aZ[0], 0, 0, 0);
        aZ[1] = MFMA16(a0, z1, aZ[1], 0, 0, 0);
        if (xp) {
            aXN[0] = MFMA16(a0, n0f, aXN[0], 0, 0, 0);
            aXN[1] = MFMA16(a0, n1f, aXN[1], 0, 0, 0);
        } else {
            aHN[0] = MFMA16(a0, n0f, aHN[0], 0, 0, 0);
            aHN[1] = MFMA16(a0, n1f, aHN[1], 0, 0, 0);
        }
    };

    STAGE(0, 0);
    __syncthreads();
#pragma unroll
    for (int s = 0; s < NS; ++s) {
        if (s + 1 < NS) STAGE((s + 1) & 1, s + 1);
        COMPUTE(s & 1, s < NSX);
        __syncthreads();
    }

#pragma unroll
    for (int fj = 0; fj < 2; ++fj) {
        const int c = c0 + wc * 32 + fj * 16 + l15;
        const float bR  = bih[c] + bhh[c];
        const float bZ  = bih[256 + c] + bhh[256 + c];
        const float bXN = bih[512 + c];
        const float bHN = bhh[512 + c];
#pragma unroll
        for (int rg = 0; rg < 4; ++rg) {
            const int n = n0 + wr * 16 + l4 * 4 + rg;
            float r  = 1.f / (1.f + __expf(-(aR[fj][rg] + bR)));
            float z  = 1.f / (1.f + __expf(-(aZ[fj][rg] + bZ)));
            float pre = aXN[fj][rg] + bXN + r * (aHN[fj][rg] + bHN);
            float nv = 2.f / (1.f + __expf(-2.f * pre)) - 1.f;
            float hp = XONLY ? 0.f : hf_in[(size_t)n * RH_ + c];
            float h  = (1.f - z) * nv + z * hp;
            outf[(size_t)n * ostride + c] = h;
            if (!XONLY) outbf[(size_t)n * RH_ + c] = f2bf(h);
        }
    }
}

// ---------------- block-diag aggregation: agg_g = A_g @ h_g (bf16 MFMA) -----
__global__ __launch_bounds__(256) void k_agg(
    const u16* __restrict__ Abf, const u16* __restrict__ hT,
    u16* __restrict__ aggbf, int C)
{
    const int g = blockIdx.x, ct = blockIdx.y;
    const int lane = threadIdx.x & 63, wave = threadIdx.x >> 6;
    const int wi = wave >> 1, wcC = wave & 1;
    const int l15 = lane & 15, l4 = lane >> 4;
    f32x4 acc[2][2] = {};
#pragma unroll
    for (int kc = 0; kc < 2; kc++) {
        bf16x8 af[2], bf_[2];
#pragma unroll
        for (int fi = 0; fi < 2; fi++)
            af[fi] = *(const bf16x8*)(Abf + ((size_t)g * 64 + wi * 32 + fi * 16 + l15) * 64
                                      + kc * 32 + l4 * 8);
#pragma unroll
        for (int fj = 0; fj < 2; fj++)
            bf_[fj] = *(const bf16x8*)(hT + (size_t)(ct * 64 + wcC * 32 + fj * 16 + l15) * NN_
                                       + g * 64 + kc * 32 + l4 * 8);
#pragma unroll
        for (int fi = 0; fi < 2; fi++)
#pragma unroll
            for (int fj = 0; fj < 2; fj++)
                acc[fi][fj] = MFMA16(af[fi], bf_[fj], acc[fi][fj], 0, 0, 0);
    }
#pragma unroll
    for (int fi = 0; fi < 2; fi++)
#pragma unroll
        for (int fj = 0; fj < 2; fj++)
#pragma unroll
            for (int rg = 0; rg < 4; rg++) {
                int n = g * 64 + wi * 32 + fi * 16 + l4 * 4 + rg;
                int c = ct * 64 + wcC * 32 + fj * 16 + l15;
                aggbf[(size_t)n * C + c] = f2bf(acc[fi][fj][rg]);
            }
}

// ---------------- GCN GEMM (bf16 MFMA): out = relu(agg @ W + b) -------------
template<int K>
__global__ __launch_bounds__(256) void k_gcnM(
    const u16* __restrict__ Ag, const u16* __restrict__ Wt,
    const float* __restrict__ bias, float* __restrict__ outF)
{
    __shared__ __align__(16) u16 As[2][64 * 32];
    __shared__ __align__(16) u16 Bs[2][64 * 32];
    const int tid = threadIdx.x;
    const int n0 = blockIdx.x * 64, c0 = blockIdx.y * 64;
    const int sr = tid >> 2, sq = tid & 3;
    const u16* pa = Ag + (size_t)(n0 + sr) * K + sq * 8;
    const u16* pb = Wt + (size_t)(c0 + sr) * K + sq * 8;

    const int lane = tid & 63, wave = tid >> 6;
    const int wr = wave >> 1, wc = wave & 1;
    const int l15 = lane & 15, l4 = lane >> 4;
    const int aoff = (wr * 32 + l15) * 32 + l4 * 8;
    const int boff = (wc * 32 + l15) * 32 + l4 * 8;
    f32x4 acc[2][2] = {};

    gload16(pa, &As[0][tid * 8]);
    gload16(pb, &Bs[0][tid * 8]);
    __syncthreads();
    constexpr int NSK = K / 32;
#pragma unroll
    for (int s = 0; s < NSK; s++) {
        if (s + 1 < NSK) {
            gload16(pa + (s + 1) * 32, &As[(s + 1) & 1][tid * 8]);
            gload16(pb + (s + 1) * 32, &Bs[(s + 1) & 1][tid * 8]);
        }
        const int b = s & 1;
        bf16x8 a0 = *(const bf16x8*)&As[b][aoff];
        bf16x8 a1 = *(const bf16x8*)&As[b][aoff + 512];
        bf16x8 b0 = *(const bf16x8*)&Bs[b][boff];
        bf16x8 b1 = *(const bf16x8*)&Bs[b][boff + 512];
        acc[0][0] = MFMA16(a0, b0, acc[0][0], 0, 0, 0);
        acc[0][1] = MFMA16(a0, b1, acc[0][1], 0, 0, 0);
        acc[1][0] = MFMA16(a1, b0, acc[1][0], 0, 0, 0);
        acc[1][1] = MFMA16(a1, b1, acc[1][1], 0, 0, 0);
        __syncthreads();
    }
#pragma unroll
    for (int fj = 0; fj < 2; fj++) {
        const int c = c0 + wc * 32 + fj * 16 + l15;
        const float bb = bias[c];
#pragma unroll
        for (int fi = 0; fi < 2; fi++)
#pragma unroll
            for (int rg = 0; rg < 4; rg++) {
                const int n = n0 + wr * 32 + fi * 16 + l4 * 4 + rg;
                outF[(size_t)n * 256 + c] = fmaxf(acc[fi][fj][rg] + bb, 0.f);
            }
    }
}

// ---------------- readout ----------------
__global__ void k_readout(const float* __restrict__ h, const int* __restrict__ gid,
                          const int* __restrict__ ntype, float* __restrict__ out,
                          float* __restrict__ cnt)
{
    for (int idx = blockIdx.x * blockDim.x + threadIdx.x; idx < NN_ * 256;
         idx += gridDim.x * blockDim.x) {
        int n = idx >> 8, c = idx & 255;
        float v = h[idx];
        int g = gid[n], t = ntype[n];
        if (t == 0) {
            atomicAdd(&out[g * 256 + c], v);
            if (c == 0) atomicAdd(&cnt[g], 1.f);
        } else if (t == 1) {
            atomicAdd(&out[16384 + g * 256 + c], v);
        } else {
            atomicAdd(&out[32768 + g * 256 + c], v);
        }
    }
}

__global__ void k_finalize(float* __restrict__ out, const float* __restrict__ cnt)
{
    int idx = blockIdx.x * blockDim.x + threadIdx.x;  // < 16384
    out[idx] /= cnt[idx >> 8];
}

// ---------------- host ----------------
extern "C" void kernel_launch(void* const* d_in, const int* in_sizes, int n_in,
                              void* d_out, int out_size, void* d_ws, size_t ws_size,
                              hipStream_t stream)
{
    const int*   tokens = (const int*)d_in[0];
    const int*   esrc   = (const int*)d_in[1];
    const int*   edst   = (const int*)d_in[2];
    const int*   gid    = (const int*)d_in[3];
    const int*   ntype  = (const int*)d_in[4];
    const float* emb    = (const float*)d_in[5];
    const float* W_ih_f = (const float*)d_in[6];
    const float* W_hh_f = (const float*)d_in[7];
    const float* b_ih_f = (const float*)d_in[8];
    const float* b_hh_f = (const float*)d_in[9];
    const float* W_ih_b = (const float*)d_in[10];
    const float* b_ih_b = (const float*)d_in[12];
    const float* b_hh_b = (const float*)d_in[13];
    const float* Wg[4]  = {(const float*)d_in[14], (const float*)d_in[16],
                           (const float*)d_in[18], (const float*)d_in[20]};
    const float* bg[4]  = {(const float*)d_in[15], (const float*)d_in[17],
                           (const float*)d_in[19], (const float*)d_in[21]};
    float* out = (float*)d_out;

    // workspace layout (16B aligned)
    float* hF    = (float*)d_ws;                        // [4096][256] f32
    u16*   embbf = (u16*)(hF + (size_t)NN_ * RH_);      // [32000][320]
    u16*   wxf   = embbf + 32000L * DINP;               // [768][320]
    u16*   whf   = wxf + (size_t)G3_ * DINP;            // [768][256]
    u16*   wxb   = whf + (size_t)G3_ * RH_;             // [768][320]
    u16*   wtg   = wxb + (size_t)G3_ * DINP;            // [256][512] max
    u16*   Abf   = wtg + 256L * 512;                    // [64][64][64]
    u16*   hT    = Abf + 64L * 64 * 64;                 // [512][4096] max
    u16*   aggb  = hT + 512L * NN_;                     // [4096][512] max
    u16*   XPROJ = aggb + (size_t)NN_ * 512;            // [32000][768]
    float* Af    = (float*)(XPROJ + 32000L * G3_);      // [64][64][64] f32
    float* HA    = Af + 64L * 64 * 64;                  // [4096][512] f32
    float* CNT   = HA + (size_t)NN_ * 512;              // [64]

    // one-time conversions + adjacency build
    k_cvt<<<2048, 256, 0, stream>>>(emb, embbf, 32000, DIN, DINP);
    k_cvt<<<256, 256, 0, stream>>>(W_ih_f, wxf, G3_, DIN, DINP);
    k_cvt<<<256, 256, 0, stream>>>(W_hh_f, whf, G3_, RH_, RH_);
    k_cvt<<<256, 256, 0, stream>>>(W_ih_b, wxb, G3_, DIN, DINP);
    k_zero<<<256, 256, 0, stream>>>(Af, 64L * 64 * 64);
    k_buildA<<<256, 256, 0, stream>>>(esrc, edst, Af);
    k_cvt<<<256, 256, 0, stream>>>(Af, Abf, 64 * 64, 64, 64);

    // XPROJ table then the whole forward scan in ONE kernel
    k_xproj<<<dim3(500, 12), 256, 0, stream>>>(embbf, wxf, b_ih_f, b_hh_f, XPROJ);
    k_scan<<<256, 512, 0, stream>>>(tokens, XPROJ, whf, b_hh_f, HA);

    // backward GRU single cell on x[:,T-1] -> HA cols 256..511
    k_step<true><<<dim3(128, 4), 256, 0, stream>>>(
        tokens, TT_ - 1, embbf, wxb, nullptr, b_ih_b, b_hh_b,
        nullptr, nullptr, HA + 256, 512, nullptr);

    // GCN: hT <- transpose(h); agg <- blockdiag(A) @ h; h <- relu(agg @ W + b)
    k_trans<<<dim3(64, 8), 256, 0, stream>>>(HA, 512, hT);
    for (int l = 0; l < 4; l++) {
        int K = (l == 0) ? 512 : 256;
        k_cvtT<<<128, 256, 0, stream>>>(Wg[l], wtg, K);
        k_agg<<<dim3(64, K / 64), 256, 0, stream>>>(Abf, hT, aggb, K);
        if (K == 512)
            k_gcnM<512><<<dim3(64, 4), 256, 0, stream>>>(aggb, wtg, bg[l], hF);
        else
            k_gcnM<256><<<dim3(64, 4), 256, 0, stream>>>(aggb, wtg, bg[l], hF);
        if (l < 3) k_trans<<<dim3(64, 4), 256, 0, stream>>>(hF, 256, hT);
    }

    // readout
    k_zero<<<256, 256, 0, stream>>>(out, 49152);
    k_zero<<<1, 64, 0, stream>>>(CNT, 64);
    k_readout<<<2048, 256, 0, stream>>>(hF, gid, ntype, out, CNT);
    k_finalize<<<64, 256, 0, stream>>>(out, CNT);
}